// Round 1
// baseline (3479.861 us; speedup 1.0000x reference)
//
#include <hip/hip_runtime.h>
#include <math.h>

#define NB 50000
#define NE 600000
#define NG 2000
#define ND 64
#define HID 128
#define BN_EPS 1e-5f

// ---------------- degree / normalization ----------------
__global__ __launch_bounds__(256) void deg_kernel(const int* __restrict__ dst,
                                                  int* __restrict__ cnt) {
  int e = blockIdx.x * 256 + threadIdx.x;
  if (e < NE) atomicAdd(&cnt[dst[e]], 1);
}

__global__ __launch_bounds__(256) void dis_kernel(const int* __restrict__ cnt,
                                                  float* __restrict__ dis) {
  int v = blockIdx.x * 256 + threadIdx.x;
  if (v < NB) dis[v] = rsqrtf((float)(cnt[v] + 1));  // +1 self-loop
}

// ---------------- GEMM: C[M,128] = A[M,K] @ B[K,128] (+bias, opt relu) -----
// BM=64, BN=128, BK=32; 256 threads; each thread: 4 rows x 8 cols.
template <bool RELU>
__global__ __launch_bounds__(256) void gemm128(const float* __restrict__ A,
                                               const float* __restrict__ B,
                                               const float* __restrict__ bias,
                                               float* __restrict__ C, int M,
                                               int K) {
  __shared__ float As[64 * 33];    // [m][k], stride 33 (conflict-free reads)
  __shared__ float Bs[32 * 132];   // [k][c], stride 132 (16B-aligned float4)
  const int tid = threadIdx.x;
  const int cg = tid & 15;         // 16 col-groups * 8 cols
  const int mg = tid >> 4;         // 16 row-groups * 4 rows
  const int mbase = blockIdx.x * 64;
  const int c0 = cg * 8;

  float acc[4][8];
#pragma unroll
  for (int i = 0; i < 4; i++)
#pragma unroll
    for (int j = 0; j < 8; j++) acc[i][j] = 0.f;

  for (int kb = 0; kb < K; kb += 32) {
    // stage A tile: 64 rows x 32 cols = 512 float4
#pragma unroll
    for (int l = 0; l < 2; l++) {
      int q = l * 256 + tid;
      int m = q >> 3, f4 = q & 7;
      int row = mbase + m;
      float4 v = make_float4(0.f, 0.f, 0.f, 0.f);
      if (row < M)
        v = *reinterpret_cast<const float4*>(A + (size_t)row * K + kb + f4 * 4);
      As[m * 33 + f4 * 4 + 0] = v.x;
      As[m * 33 + f4 * 4 + 1] = v.y;
      As[m * 33 + f4 * 4 + 2] = v.z;
      As[m * 33 + f4 * 4 + 3] = v.w;
    }
    // stage B tile: 32 rows x 128 cols = 1024 float4
#pragma unroll
    for (int l = 0; l < 4; l++) {
      int q = l * 256 + tid;
      int k = q >> 5, f4 = q & 31;
      float4 v =
          *reinterpret_cast<const float4*>(B + (size_t)(kb + k) * 128 + f4 * 4);
      *reinterpret_cast<float4*>(&Bs[k * 132 + f4 * 4]) = v;
    }
    __syncthreads();
#pragma unroll
    for (int k = 0; k < 32; k++) {
      float a0 = As[(mg * 4 + 0) * 33 + k];
      float a1 = As[(mg * 4 + 1) * 33 + k];
      float a2 = As[(mg * 4 + 2) * 33 + k];
      float a3 = As[(mg * 4 + 3) * 33 + k];
      float4 b0 = *reinterpret_cast<const float4*>(&Bs[k * 132 + c0]);
      float4 b1 = *reinterpret_cast<const float4*>(&Bs[k * 132 + c0 + 4]);
      acc[0][0] += a0 * b0.x; acc[0][1] += a0 * b0.y; acc[0][2] += a0 * b0.z; acc[0][3] += a0 * b0.w;
      acc[0][4] += a0 * b1.x; acc[0][5] += a0 * b1.y; acc[0][6] += a0 * b1.z; acc[0][7] += a0 * b1.w;
      acc[1][0] += a1 * b0.x; acc[1][1] += a1 * b0.y; acc[1][2] += a1 * b0.z; acc[1][3] += a1 * b0.w;
      acc[1][4] += a1 * b1.x; acc[1][5] += a1 * b1.y; acc[1][6] += a1 * b1.z; acc[1][7] += a1 * b1.w;
      acc[2][0] += a2 * b0.x; acc[2][1] += a2 * b0.y; acc[2][2] += a2 * b0.z; acc[2][3] += a2 * b0.w;
      acc[2][4] += a2 * b1.x; acc[2][5] += a2 * b1.y; acc[2][6] += a2 * b1.z; acc[2][7] += a2 * b1.w;
      acc[3][0] += a3 * b0.x; acc[3][1] += a3 * b0.y; acc[3][2] += a3 * b0.z; acc[3][3] += a3 * b0.w;
      acc[3][4] += a3 * b1.x; acc[3][5] += a3 * b1.y; acc[3][6] += a3 * b1.z; acc[3][7] += a3 * b1.w;
    }
    __syncthreads();
  }

  float bv[8];
#pragma unroll
  for (int j = 0; j < 8; j++) bv[j] = bias ? bias[c0 + j] : 0.f;
#pragma unroll
  for (int i = 0; i < 4; i++) {
    int row = mbase + mg * 4 + i;
    if (row < M) {
      float o[8];
#pragma unroll
      for (int j = 0; j < 8; j++) {
        o[j] = acc[i][j] + bv[j];
        if (RELU) o[j] = fmaxf(o[j], 0.f);
      }
      float* cp = C + (size_t)row * 128 + c0;
      *reinterpret_cast<float4*>(cp) = make_float4(o[0], o[1], o[2], o[3]);
      *reinterpret_cast<float4*>(cp + 4) = make_float4(o[4], o[5], o[6], o[7]);
    }
  }
}

// ---------------- conv aggregation ----------------
// x2[v] = conv_b + h[v] * dis[v]^2   (self-loop + bias)
__global__ __launch_bounds__(256) void init_x2(const float* __restrict__ h,
                                               const float* __restrict__ dis,
                                               const float* __restrict__ bias,
                                               float* __restrict__ x2) {
  int gid = blockIdx.x * 256 + threadIdx.x;
  int v = gid >> 5, c4 = gid & 31;
  if (v >= NB) return;
  float s = dis[v];
  s = s * s;
  float4 hv = reinterpret_cast<const float4*>(h)[(size_t)v * 32 + c4];
  float4 b = reinterpret_cast<const float4*>(bias)[c4];
  float4 o;
  o.x = b.x + hv.x * s;
  o.y = b.y + hv.y * s;
  o.z = b.z + hv.z * s;
  o.w = b.w + hv.w * s;
  reinterpret_cast<float4*>(x2)[(size_t)v * 32 + c4] = o;
}

// x2[dst] += h[src] * dis[src]*dis[dst], 32 lanes per edge (4 ch each)
__global__ __launch_bounds__(256) void edge_kernel(const float* __restrict__ h,
                                                   const int* __restrict__ src,
                                                   const int* __restrict__ dst,
                                                   const float* __restrict__ dis,
                                                   float* __restrict__ x2) {
  int gid = blockIdx.x * 256 + threadIdx.x;
  int e = gid >> 5;
  if (e >= NE) return;
  int c4 = gid & 31;
  int s = src[e], d = dst[e];
  float w = dis[s] * dis[d];
  float4 v = reinterpret_cast<const float4*>(h)[(size_t)s * 32 + c4];
  float* o = x2 + (size_t)d * 128 + c4 * 4;
  atomicAdd(o + 0, v.x * w);
  atomicAdd(o + 1, v.y * w);
  atomicAdd(o + 2, v.z * w);
  atomicAdd(o + 3, v.w * w);
}

// relu in place + per-channel sum / sumsq partials -> stats[0..127]=sum, [128..255]=sumsq
__global__ __launch_bounds__(256) void relu_stats(float* __restrict__ x,
                                                  float* __restrict__ stats) {
  __shared__ float ssum[256], ssq[256];
  int tid = threadIdx.x;
  int c = tid & 127;  // idx%128 == tid%128 for stride-256 loops
  float sum = 0.f, sq = 0.f;
  for (int idx = blockIdx.x * 256 + tid; idx < NB * HID;
       idx += gridDim.x * 256) {
    float v = x[idx];
    v = fmaxf(v, 0.f);
    x[idx] = v;
    sum += v;
    sq += v * v;
  }
  ssum[tid] = sum;
  ssq[tid] = sq;
  __syncthreads();
  if (tid < 128) {
    atomicAdd(&stats[c], ssum[tid] + ssum[tid + 128]);
    atomicAdd(&stats[128 + c], ssq[tid] + ssq[tid + 128]);
  }
}

// x = (x - mu) * gamma * rsqrt(var+eps) + beta, in place
__global__ __launch_bounds__(256) void bn_scale(float* __restrict__ x,
                                                const float* __restrict__ stats,
                                                const float* __restrict__ gamma,
                                                const float* __restrict__ beta) {
  int tid = threadIdx.x;
  int c = tid & 127;
  float mu = stats[c] * (1.0f / NB);
  float var = stats[128 + c] * (1.0f / NB) - mu * mu;
  float a = gamma[c] * rsqrtf(var + BN_EPS);
  float b = beta[c] - mu * a;
  for (int idx = blockIdx.x * 256 + tid; idx < NB * HID;
       idx += gridDim.x * 256)
    x[idx] = x[idx] * a + b;
}

// g[batch[v]] += emb[v]
__global__ __launch_bounds__(256) void pool_kernel(const float* __restrict__ emb,
                                                   const int* __restrict__ batch,
                                                   float* __restrict__ g) {
  int gid = blockIdx.x * 256 + threadIdx.x;
  int v = gid >> 5, c4 = gid & 31;
  if (v >= NB) return;
  int b = batch[v];
  float4 e = reinterpret_cast<const float4*>(emb)[(size_t)v * 32 + c4];
  float* o = g + (size_t)b * 128 + c4 * 4;
  atomicAdd(o + 0, e.x);
  atomicAdd(o + 1, e.y);
  atomicAdd(o + 2, e.z);
  atomicAdd(o + 3, e.w);
}

// per-graph MLP head: 128 -> 64 -> 32 -> 2
__global__ __launch_bounds__(128) void head_kernel(
    const float* __restrict__ g, const float* __restrict__ w1,
    const float* __restrict__ b1, const float* __restrict__ w2,
    const float* __restrict__ b2, const float* __restrict__ wp,
    const float* __restrict__ bp, float* __restrict__ out) {
  __shared__ float sg[128];
  __shared__ float sh1[64];
  __shared__ float sh2[32];
  int tid = threadIdx.x;
  int gid = blockIdx.x;
  sg[tid] = g[(size_t)gid * 128 + tid];
  __syncthreads();
  if (tid < 64) {
    float acc = b1[tid];
#pragma unroll 8
    for (int k = 0; k < 128; k++) acc += sg[k] * w1[k * 64 + tid];
    sh1[tid] = fmaxf(acc, 0.f);
  }
  __syncthreads();
  if (tid < 32) {
    float acc = b2[tid];
#pragma unroll 8
    for (int k = 0; k < 64; k++) acc += sh1[k] * w2[k * 32 + tid];
    sh2[tid] = fmaxf(acc, 0.f);
  }
  __syncthreads();
  if (tid < 2) {
    float acc = bp[tid];
#pragma unroll
    for (int k = 0; k < 32; k++) acc += sh2[k] * wp[k * 2 + tid];
    out[(size_t)gid * 2 + tid] = acc;
  }
}

extern "C" void kernel_launch(void* const* d_in, const int* in_sizes, int n_in,
                              void* d_out, int out_size, void* d_ws,
                              size_t ws_size, hipStream_t stream) {
  const float* x = (const float*)d_in[0];
  const int* ei = (const int*)d_in[1];
  const int* batch = (const int*)d_in[2];
  const float* lin_w = (const float*)d_in[3];
  const float* lin_b = (const float*)d_in[4];
  const float* conv_w = (const float*)d_in[5];
  const float* conv_b = (const float*)d_in[6];
  const float* bn_g = (const float*)d_in[7];
  const float* bn_b = (const float*)d_in[8];
  const float* emb_w = (const float*)d_in[9];
  const float* emb_b = (const float*)d_in[10];
  const float* m1w = (const float*)d_in[11];
  const float* m1b = (const float*)d_in[12];
  const float* m2w = (const float*)d_in[13];
  const float* m2b = (const float*)d_in[14];
  const float* pw = (const float*)d_in[15];
  const float* pb = (const float*)d_in[16];
  float* out = (float*)d_out;

  float* ws = (float*)d_ws;
  float* buf0 = ws;                              // [NB,128] current x
  float* buf1 = buf0 + (size_t)NB * HID;         // [NB,128] h / emb
  float* dis = buf1 + (size_t)NB * HID;          // [NB]
  float* stats = dis + 50048;                    // [256] (aligned)
  float* g = stats + 256;                        // [NG,128]
  int* cnt = (int*)(g + (size_t)NG * HID);       // [NB]

  const int* src = ei;
  const int* dst = ei + NE;

  hipMemsetAsync(cnt, 0, NB * sizeof(int), stream);
  hipMemsetAsync(g, 0, (size_t)NG * HID * sizeof(float), stream);

  deg_kernel<<<(NE + 255) / 256, 256, 0, stream>>>(dst, cnt);
  dis_kernel<<<(NB + 255) / 256, 256, 0, stream>>>(cnt, dis);

  // linatoms: x1 = x @ lin_w + lin_b
  gemm128<false><<<(NB + 63) / 64, 256, 0, stream>>>(x, lin_w, lin_b, buf0, NB,
                                                     ND);

  for (int i = 0; i < 3; i++) {
    gemm128<false><<<(NB + 63) / 64, 256, 0, stream>>>(
        buf0, conv_w + (size_t)i * HID * HID, nullptr, buf1, NB, HID);
    init_x2<<<(NB * 32 + 255) / 256, 256, 0, stream>>>(buf1, dis,
                                                       conv_b + i * HID, buf0);
    edge_kernel<<<(NE * 32 + 255) / 256, 256, 0, stream>>>(buf1, src, dst, dis,
                                                           buf0);
    hipMemsetAsync(stats, 0, 256 * sizeof(float), stream);
    relu_stats<<<512, 256, 0, stream>>>(buf0, stats);
    bn_scale<<<512, 256, 0, stream>>>(buf0, stats, bn_g + i * HID,
                                      bn_b + i * HID);
  }

  // graph_emb: relu(x @ emb_w + emb_b)
  gemm128<true><<<(NB + 63) / 64, 256, 0, stream>>>(buf0, emb_w, emb_b, buf1,
                                                    NB, HID);
  pool_kernel<<<(NB * 32 + 255) / 256, 256, 0, stream>>>(buf1, batch, g);
  head_kernel<<<NG, 128, 0, stream>>>(g, m1w, m1b, m2w, m2b, pw, pb, out);
}

// Round 2
// 529.603 us; speedup vs baseline: 6.5707x; 6.5707x over previous
//
#include <hip/hip_runtime.h>
#include <math.h>

#define NB 50000
#define NE 600000
#define NG 2000
#define ND 64
#define HID 128
#define BN_EPS 1e-5f
#define NBLK 196  // ceil(NB/256)

// ---------------- degree / normalization ----------------
__global__ __launch_bounds__(256) void deg_kernel(const int* __restrict__ dst,
                                                  int* __restrict__ cnt) {
  int e = blockIdx.x * 256 + threadIdx.x;
  if (e < NE) atomicAdd(&cnt[dst[e]], 1);
}

__global__ __launch_bounds__(256) void dis_kernel(const int* __restrict__ cnt,
                                                  float* __restrict__ dis) {
  int v = blockIdx.x * 256 + threadIdx.x;
  if (v < NB) dis[v] = rsqrtf((float)(cnt[v] + 1));  // +1 self-loop
}

// ---------------- prefix scan (row_ptr = exclusive scan of cnt) -----------
__global__ __launch_bounds__(256) void scan1(const int* __restrict__ cnt,
                                             int* __restrict__ part,
                                             int* __restrict__ bsum) {
  __shared__ int tmp[256];
  int tid = threadIdx.x;
  int i = blockIdx.x * 256 + tid;
  int v = (i < NB) ? cnt[i] : 0;
  tmp[tid] = v;
  __syncthreads();
  for (int off = 1; off < 256; off <<= 1) {
    int t = (tid >= off) ? tmp[tid - off] : 0;
    __syncthreads();
    tmp[tid] += t;
    __syncthreads();
  }
  if (i < NB) part[i] = tmp[tid] - v;  // exclusive within block
  if (tid == 255) bsum[blockIdx.x] = tmp[255];
}

__global__ __launch_bounds__(256) void scan2(int* __restrict__ bsum,
                                             int* __restrict__ boffs) {
  __shared__ int tmp[256];
  int tid = threadIdx.x;
  int v = (tid < NBLK) ? bsum[tid] : 0;
  tmp[tid] = v;
  __syncthreads();
  for (int off = 1; off < 256; off <<= 1) {
    int t = (tid >= off) ? tmp[tid - off] : 0;
    __syncthreads();
    tmp[tid] += t;
    __syncthreads();
  }
  if (tid < NBLK) boffs[tid] = tmp[tid] - v;
}

__global__ __launch_bounds__(256) void scan3(int* __restrict__ part,
                                             const int* __restrict__ boffs) {
  int i = blockIdx.x * 256 + threadIdx.x;
  if (i < NB) part[i] += boffs[blockIdx.x];
  if (i == 0) part[NB] = NE;
}

// ---------------- CSR fill (sorted-by-dst edge list) ----------------------
__global__ __launch_bounds__(256) void fill_csr(const int* __restrict__ src,
                                                const int* __restrict__ dst,
                                                const float* __restrict__ dis,
                                                const int* __restrict__ row_ptr,
                                                int* __restrict__ cursor,
                                                int* __restrict__ e_src,
                                                float* __restrict__ e_w) {
  int e = blockIdx.x * 256 + threadIdx.x;
  if (e >= NE) return;
  int s = src[e], d = dst[e];
  int pos = row_ptr[d] + atomicAdd(&cursor[d], 1);
  e_src[pos] = s;
  e_w[pos] = dis[s] * dis[d];
}

// ---------------- GEMM: C[M,128] = A[M,K] @ B[K,128] (+bias, opt relu) ----
template <bool RELU>
__global__ __launch_bounds__(256) void gemm128(const float* __restrict__ A,
                                               const float* __restrict__ B,
                                               const float* __restrict__ bias,
                                               float* __restrict__ C, int M,
                                               int K) {
  __shared__ float As[64 * 33];
  __shared__ float Bs[32 * 132];
  const int tid = threadIdx.x;
  const int cg = tid & 15;
  const int mg = tid >> 4;
  const int mbase = blockIdx.x * 64;
  const int c0 = cg * 8;

  float acc[4][8];
#pragma unroll
  for (int i = 0; i < 4; i++)
#pragma unroll
    for (int j = 0; j < 8; j++) acc[i][j] = 0.f;

  for (int kb = 0; kb < K; kb += 32) {
#pragma unroll
    for (int l = 0; l < 2; l++) {
      int q = l * 256 + tid;
      int m = q >> 3, f4 = q & 7;
      int row = mbase + m;
      float4 v = make_float4(0.f, 0.f, 0.f, 0.f);
      if (row < M)
        v = *reinterpret_cast<const float4*>(A + (size_t)row * K + kb + f4 * 4);
      As[m * 33 + f4 * 4 + 0] = v.x;
      As[m * 33 + f4 * 4 + 1] = v.y;
      As[m * 33 + f4 * 4 + 2] = v.z;
      As[m * 33 + f4 * 4 + 3] = v.w;
    }
#pragma unroll
    for (int l = 0; l < 4; l++) {
      int q = l * 256 + tid;
      int k = q >> 5, f4 = q & 31;
      float4 v =
          *reinterpret_cast<const float4*>(B + (size_t)(kb + k) * 128 + f4 * 4);
      *reinterpret_cast<float4*>(&Bs[k * 132 + f4 * 4]) = v;
    }
    __syncthreads();
#pragma unroll
    for (int k = 0; k < 32; k++) {
      float a0 = As[(mg * 4 + 0) * 33 + k];
      float a1 = As[(mg * 4 + 1) * 33 + k];
      float a2 = As[(mg * 4 + 2) * 33 + k];
      float a3 = As[(mg * 4 + 3) * 33 + k];
      float4 b0 = *reinterpret_cast<const float4*>(&Bs[k * 132 + c0]);
      float4 b1 = *reinterpret_cast<const float4*>(&Bs[k * 132 + c0 + 4]);
      acc[0][0] += a0 * b0.x; acc[0][1] += a0 * b0.y; acc[0][2] += a0 * b0.z; acc[0][3] += a0 * b0.w;
      acc[0][4] += a0 * b1.x; acc[0][5] += a0 * b1.y; acc[0][6] += a0 * b1.z; acc[0][7] += a0 * b1.w;
      acc[1][0] += a1 * b0.x; acc[1][1] += a1 * b0.y; acc[1][2] += a1 * b0.z; acc[1][3] += a1 * b0.w;
      acc[1][4] += a1 * b1.x; acc[1][5] += a1 * b1.y; acc[1][6] += a1 * b1.z; acc[1][7] += a1 * b1.w;
      acc[2][0] += a2 * b0.x; acc[2][1] += a2 * b0.y; acc[2][2] += a2 * b0.z; acc[2][3] += a2 * b0.w;
      acc[2][4] += a2 * b1.x; acc[2][5] += a2 * b1.y; acc[2][6] += a2 * b1.z; acc[2][7] += a2 * b1.w;
      acc[3][0] += a3 * b0.x; acc[3][1] += a3 * b0.y; acc[3][2] += a3 * b0.z; acc[3][3] += a3 * b0.w;
      acc[3][4] += a3 * b1.x; acc[3][5] += a3 * b1.y; acc[3][6] += a3 * b1.z; acc[3][7] += a3 * b1.w;
    }
    __syncthreads();
  }

  float bv[8];
#pragma unroll
  for (int j = 0; j < 8; j++) bv[j] = bias ? bias[c0 + j] : 0.f;
#pragma unroll
  for (int i = 0; i < 4; i++) {
    int row = mbase + mg * 4 + i;
    if (row < M) {
      float o[8];
#pragma unroll
      for (int j = 0; j < 8; j++) {
        o[j] = acc[i][j] + bv[j];
        if (RELU) o[j] = fmaxf(o[j], 0.f);
      }
      float* cp = C + (size_t)row * 128 + c0;
      *reinterpret_cast<float4*>(cp) = make_float4(o[0], o[1], o[2], o[3]);
      *reinterpret_cast<float4*>(cp + 4) = make_float4(o[4], o[5], o[6], o[7]);
    }
  }
}

// ---------------- conv aggregation: CSR gather (no atomics) ---------------
// x2[v] = bias + h[v]*dis[v]^2 + sum_{e in in(v)} h[e_src[e]] * e_w[e]
__global__ __launch_bounds__(256) void gather_conv(
    const float* __restrict__ h, const int* __restrict__ e_src,
    const float* __restrict__ e_w, const int* __restrict__ row_ptr,
    const float* __restrict__ dis, const float* __restrict__ bias,
    float* __restrict__ x2) {
  int gid = blockIdx.x * 256 + threadIdx.x;
  int v = gid >> 5;
  if (v >= NB) return;
  int c4 = gid & 31;
  const float4* h4 = reinterpret_cast<const float4*>(h);
  float s = dis[v];
  float ss = s * s;
  float4 b = reinterpret_cast<const float4*>(bias)[c4];
  float4 hv = h4[(size_t)v * 32 + c4];
  float4 acc =
      make_float4(b.x + hv.x * ss, b.y + hv.y * ss, b.z + hv.z * ss,
                  b.w + hv.w * ss);
  int beg = row_ptr[v], end = row_ptr[v + 1];
  for (int e = beg; e < end; ++e) {
    int si = e_src[e];
    float w = e_w[e];
    float4 q = h4[(size_t)si * 32 + c4];
    acc.x += q.x * w;
    acc.y += q.y * w;
    acc.z += q.z * w;
    acc.w += q.w * w;
  }
  reinterpret_cast<float4*>(x2)[(size_t)v * 32 + c4] = acc;
}

// relu in place + per-channel sum / sumsq -> stats[0..127]=sum,[128..255]=sumsq
__global__ __launch_bounds__(256) void relu_stats(float* __restrict__ x,
                                                  float* __restrict__ stats) {
  __shared__ float ssum[256], ssq[256];
  int tid = threadIdx.x;
  int c = tid & 127;
  float sum = 0.f, sq = 0.f;
  for (int idx = blockIdx.x * 256 + tid; idx < NB * HID;
       idx += gridDim.x * 256) {
    float v = x[idx];
    v = fmaxf(v, 0.f);
    x[idx] = v;
    sum += v;
    sq += v * v;
  }
  ssum[tid] = sum;
  ssq[tid] = sq;
  __syncthreads();
  if (tid < 128) {
    atomicAdd(&stats[c], ssum[tid] + ssum[tid + 128]);
    atomicAdd(&stats[128 + c], ssq[tid] + ssq[tid + 128]);
  }
}

__global__ __launch_bounds__(256) void bn_scale(float* __restrict__ x,
                                                const float* __restrict__ stats,
                                                const float* __restrict__ gamma,
                                                const float* __restrict__ beta) {
  int tid = threadIdx.x;
  int c = tid & 127;
  float mu = stats[c] * (1.0f / NB);
  float var = stats[128 + c] * (1.0f / NB) - mu * mu;
  float a = gamma[c] * rsqrtf(var + BN_EPS);
  float b = beta[c] - mu * a;
  for (int idx = blockIdx.x * 256 + tid; idx < NB * HID;
       idx += gridDim.x * 256)
    x[idx] = x[idx] * a + b;
}

// ---------------- pooling: segmented gather over sorted batch -------------
__global__ __launch_bounds__(256) void graph_bounds(const int* __restrict__ batch,
                                                    int* __restrict__ g_start) {
  int g = blockIdx.x * 256 + threadIdx.x;
  if (g > NG) return;
  if (g == NG) {
    g_start[NG] = NB;
    return;
  }
  int lo = 0, hi = NB;
  while (lo < hi) {
    int mid = (lo + hi) >> 1;
    if (batch[mid] < g)
      lo = mid + 1;
    else
      hi = mid;
  }
  g_start[g] = lo;
}

__global__ __launch_bounds__(256) void pool_gather(const float* __restrict__ emb,
                                                   const int* __restrict__ g_start,
                                                   float* __restrict__ g) {
  int gid = blockIdx.x * 256 + threadIdx.x;
  int gr = gid >> 5;
  if (gr >= NG) return;
  int c4 = gid & 31;
  const float4* e4 = reinterpret_cast<const float4*>(emb);
  float4 acc = make_float4(0.f, 0.f, 0.f, 0.f);
  int beg = g_start[gr], end = g_start[gr + 1];
  for (int v = beg; v < end; ++v) {
    float4 e = e4[(size_t)v * 32 + c4];
    acc.x += e.x;
    acc.y += e.y;
    acc.z += e.z;
    acc.w += e.w;
  }
  reinterpret_cast<float4*>(g)[(size_t)gr * 32 + c4] = acc;
}

// per-graph MLP head: 128 -> 64 -> 32 -> 2
__global__ __launch_bounds__(128) void head_kernel(
    const float* __restrict__ g, const float* __restrict__ w1,
    const float* __restrict__ b1, const float* __restrict__ w2,
    const float* __restrict__ b2, const float* __restrict__ wp,
    const float* __restrict__ bp, float* __restrict__ out) {
  __shared__ float sg[128];
  __shared__ float sh1[64];
  __shared__ float sh2[32];
  int tid = threadIdx.x;
  int gid = blockIdx.x;
  sg[tid] = g[(size_t)gid * 128 + tid];
  __syncthreads();
  if (tid < 64) {
    float acc = b1[tid];
#pragma unroll 8
    for (int k = 0; k < 128; k++) acc += sg[k] * w1[k * 64 + tid];
    sh1[tid] = fmaxf(acc, 0.f);
  }
  __syncthreads();
  if (tid < 32) {
    float acc = b2[tid];
#pragma unroll 8
    for (int k = 0; k < 64; k++) acc += sh1[k] * w2[k * 32 + tid];
    sh2[tid] = fmaxf(acc, 0.f);
  }
  __syncthreads();
  if (tid < 2) {
    float acc = bp[tid];
#pragma unroll
    for (int k = 0; k < 32; k++) acc += sh2[k] * wp[k * 2 + tid];
    out[(size_t)gid * 2 + tid] = acc;
  }
}

extern "C" void kernel_launch(void* const* d_in, const int* in_sizes, int n_in,
                              void* d_out, int out_size, void* d_ws,
                              size_t ws_size, hipStream_t stream) {
  const float* x = (const float*)d_in[0];
  const int* ei = (const int*)d_in[1];
  const int* batch = (const int*)d_in[2];
  const float* lin_w = (const float*)d_in[3];
  const float* lin_b = (const float*)d_in[4];
  const float* conv_w = (const float*)d_in[5];
  const float* conv_b = (const float*)d_in[6];
  const float* bn_g = (const float*)d_in[7];
  const float* bn_b = (const float*)d_in[8];
  const float* emb_w = (const float*)d_in[9];
  const float* emb_b = (const float*)d_in[10];
  const float* m1w = (const float*)d_in[11];
  const float* m1b = (const float*)d_in[12];
  const float* m2w = (const float*)d_in[13];
  const float* m2b = (const float*)d_in[14];
  const float* pw = (const float*)d_in[15];
  const float* pb = (const float*)d_in[16];
  float* out = (float*)d_out;

  float* ws = (float*)d_ws;
  float* buf0 = ws;                               // [NB,128]
  float* buf1 = buf0 + (size_t)NB * HID;          // [NB,128]
  float* dis = buf1 + (size_t)NB * HID;           // [NB] (pad 50048)
  float* stats = dis + 50048;                     // [256]
  float* g = stats + 256;                         // [NG,128]
  float* e_w = g + (size_t)NG * HID;              // [NE]
  int* cnt = (int*)(e_w + NE);                    // [NB]
  int* row_ptr = cnt + NB;                        // [NB+1]
  int* cursor = row_ptr + NB + 8;                 // [NB]
  int* e_src = cursor + NB;                       // [NE]
  int* bsum = e_src + NE;                         // [256]
  int* boffs = bsum + 256;                        // [256]
  int* g_start = boffs + 256;                     // [NG+1]

  const int* src = ei;
  const int* dst = ei + NE;

  hipMemsetAsync(cnt, 0, NB * sizeof(int), stream);
  hipMemsetAsync(cursor, 0, NB * sizeof(int), stream);

  // degree + normalization
  deg_kernel<<<(NE + 255) / 256, 256, 0, stream>>>(dst, cnt);
  dis_kernel<<<NBLK, 256, 0, stream>>>(cnt, dis);

  // CSR build: row_ptr = exscan(cnt); fill sorted-by-dst edge arrays
  scan1<<<NBLK, 256, 0, stream>>>(cnt, row_ptr, bsum);
  scan2<<<1, 256, 0, stream>>>(bsum, boffs);
  scan3<<<NBLK, 256, 0, stream>>>(row_ptr, boffs);
  fill_csr<<<(NE + 255) / 256, 256, 0, stream>>>(src, dst, dis, row_ptr,
                                                 cursor, e_src, e_w);

  // graph boundaries for pooling
  graph_bounds<<<(NG + 256) / 256, 256, 0, stream>>>(batch, g_start);

  // linatoms
  gemm128<false><<<(NB + 63) / 64, 256, 0, stream>>>(x, lin_w, lin_b, buf0, NB,
                                                     ND);

  for (int i = 0; i < 3; i++) {
    gemm128<false><<<(NB + 63) / 64, 256, 0, stream>>>(
        buf0, conv_w + (size_t)i * HID * HID, nullptr, buf1, NB, HID);
    gather_conv<<<(NB * 32 + 255) / 256, 256, 0, stream>>>(
        buf1, e_src, e_w, row_ptr, dis, conv_b + i * HID, buf0);
    hipMemsetAsync(stats, 0, 256 * sizeof(float), stream);
    relu_stats<<<512, 256, 0, stream>>>(buf0, stats);
    bn_scale<<<512, 256, 0, stream>>>(buf0, stats, bn_g + i * HID,
                                      bn_b + i * HID);
  }

  gemm128<true><<<(NB + 63) / 64, 256, 0, stream>>>(buf0, emb_w, emb_b, buf1,
                                                    NB, HID);
  pool_gather<<<(NG * 32 + 255) / 256, 256, 0, stream>>>(buf1, g_start, g);
  head_kernel<<<NG, 128, 0, stream>>>(g, m1w, m1b, m2w, m2b, pw, pb, out);
}